// Round 2
// baseline (4285.580 us; speedup 1.0000x reference)
//
#include <hip/hip_runtime.h>

typedef unsigned short u16;
typedef float  f32x4 __attribute__((ext_vector_type(4)));
typedef short  s16x8 __attribute__((ext_vector_type(8)));

#define BTOT    131072
#define DIM     256
#define NLAYER  6
#define MROWS   64            // rows per block (8 waves: 2 row-groups x 4 col-groups, 32x64 tile/wave)
#define NTHR    512
#define LSTR    264           // padded bf16 row stride (16B-aligned rows; 2-way bank alias = free)
#define W2OFF   131072        // u16 elements: W2 block offset inside d_ws

__device__ __forceinline__ float bf2f(u16 u) {
    union { unsigned int i; float f; } v; v.i = ((unsigned int)u) << 16; return v.f;
}
__device__ __forceinline__ u16 f2bf(float f) {
    union { float f; unsigned int i; } v; v.f = f;
    return (u16)((v.i + 0x7fffu + ((v.i >> 16) & 1u)) >> 16);   // RNE (finite values only)
}
__device__ __forceinline__ float ftanh(float x) {
    float e = __expf(2.0f * x);          // inf-safe: e=inf -> 1, e=0 -> -1
    return 1.0f - 2.0f / (e + 1.0f);
}

// Pre-split W1/W2 (fp32) into bf16 hi/lo planes, row-blocked: ws[n*512 + k]=hi, [n*512+256+k]=lo.
__global__ void wsplit_kernel(const float* __restrict__ W1, const float* __restrict__ W2,
                              u16* __restrict__ ws) {
    int i = blockIdx.x * 256 + threadIdx.x;      // 0..65535
    int n = i >> 8, k = i & 255;
    float w1 = W1[i]; u16 h1 = f2bf(w1);
    ws[n * 512 + k]       = h1;
    ws[n * 512 + 256 + k] = f2bf(w1 - bf2f(h1));
    float w2 = W2[i]; u16 h2 = f2bf(w2);
    ws[W2OFF + n * 512 + k]       = h2;
    ws[W2OFF + n * 512 + 256 + k] = f2bf(w2 - bf2f(h2));
}

__global__ __launch_bounds__(NTHR) __attribute__((amdgpu_waves_per_eu(4, 4)))
void collapse_kernel(const float* __restrict__ h0,
                     const float* __restrict__ b1g,
                     const float* __restrict__ b2g,
                     const float* __restrict__ ancg,
                     const u16*  __restrict__ ws,
                     float* __restrict__ out)
{
    __shared__ u16   hb_hi[MROWS * LSTR];   // 33792 B: A-operand hi plane (h / z / h_new, time-shared)
    __shared__ u16   hb_lo[MROWS * LSTR];   // 33792 B: lo plane
    __shared__ float dpart[12 * MROWS];     //  3072 B: anchor-dot partials [wc*3+a][row]
    __shared__ float scal[MROWS * 8];       //  2048 B: per-row {alpha,c0,c1,c2, s, ss}
    __shared__ float anch_inv[3];

    const int t    = threadIdx.x;
    const int w    = t >> 6;                // wave 0..7
    const int ln   = t & 63;
    const int wr   = w >> 2;                // row-group 0..1 (32 rows each)
    const int wc   = w & 3;                 // col-group 0..3 (64 cols each)
    const int c15  = ln & 15;
    const int q    = ln >> 4;
    const int wcol = wc << 6;               // wave's 64-col slice
    const int wrow = wr << 5;               // wave's 32-row slice
    const int rr   = t >> 3;                // row-thread: row 0..63
    const int ch   = t & 7;                 // row-thread: 32-col chunk
    const long row0 = (long)blockIdx.x * MROWS;

    // ---------------- bootstrap ----------------
    {   // coalesced fp32 h0 -> split hi/lo planes; per-row ||h0||^2
        const f32x4* src = (const f32x4*)(h0 + (row0 + rr) * DIM + (ch << 5));
        u16* dh = hb_hi + rr * LSTR + (ch << 5);
        u16* dl = hb_lo + rr * LSTR + (ch << 5);
        float ss = 0.f;
        #pragma unroll
        for (int j = 0; j < 4; ++j) {
            f32x4 v0 = src[2 * j], v1 = src[2 * j + 1];
            s16x8 vh, vl;
            #pragma unroll
            for (int e = 0; e < 4; ++e) {
                float f = v0[e]; ss = fmaf(f, f, ss);
                u16 hi = f2bf(f); vh[e] = (short)hi; vl[e] = (short)f2bf(f - bf2f(hi));
            }
            #pragma unroll
            for (int e = 0; e < 4; ++e) {
                float f = v1[e]; ss = fmaf(f, f, ss);
                u16 hi = f2bf(f); vh[4 + e] = (short)hi; vl[4 + e] = (short)f2bf(f - bf2f(hi));
            }
            *(s16x8*)(dh + (j << 3)) = vh;
            *(s16x8*)(dl + (j << 3)) = vl;
        }
        ss += __shfl_xor(ss, 1);
        ss += __shfl_xor(ss, 2);
        ss += __shfl_xor(ss, 4);
        if (ch == 0) { scal[(rr << 3) + 4] = 1.f; scal[(rr << 3) + 5] = ss; }
    }
    if (w < 3) {                            // waves 0..2: anchor inverse norms (fp32)
        float ssa = 0.f;
        #pragma unroll
        for (int j = 0; j < 4; ++j) {
            float v = ancg[w * DIM + (ln << 2) + j];
            ssa = fmaf(v, v, ssa);
        }
        #pragma unroll
        for (int m = 1; m < 64; m <<= 1) ssa += __shfl_xor(ssa, m);
        if (ln == 0) anch_inv[w] = 1.f / fmaxf(sqrtf(ssa), 1e-12f);
    }
    __syncthreads();

    // owners: fp32 h registers in MFMA C-layout (row=wrow+16mi+4q+rg, col=wcol+16tn+c15)
    f32x4 h[2][4];
    #pragma unroll
    for (int mi = 0; mi < 2; ++mi)
      #pragma unroll
      for (int tn = 0; tn < 4; ++tn)
        #pragma unroll
        for (int rg = 0; rg < 4; ++rg) {
            int off = (wrow + 16 * mi + (q << 2) + rg) * LSTR + wcol + (tn << 4) + c15;
            h[mi][tn][rg] = bf2f(hb_hi[off]) + bf2f(hb_lo[off]);
        }
    float an[3][4], b1c[4], b2c[4];
    #pragma unroll
    for (int tn = 0; tn < 4; ++tn) {
        int c = wcol + (tn << 4) + c15;
        an[0][tn] = ancg[0 * DIM + c] * anch_inv[0];
        an[1][tn] = ancg[1 * DIM + c] * anch_inv[1];
        an[2][tn] = ancg[2 * DIM + c] * anch_inv[2];
        b1c[tn]   = b1g[c];
        b2c[tn]   = b2g[c];
    }

    const long A0  = (long)BTOT * DIM;          // traces base
    const long TRL = (long)NLAYER * BTOT * 3;   // one trace array length

    // bf16x3 GEMM: acc += (Ahi+Alo)@(Bhi+Blo), dropping lo*lo. A from LDS planes, B from ws.
    auto gemm3 = [&](const u16* wb, f32x4 (&acc)[2][4]) {
        #pragma unroll
        for (int ks = 0; ks < 8; ++ks) {
            s16x8 Ah[2], Al[2];
            #pragma unroll
            for (int mi = 0; mi < 2; ++mi) {
                int off = (wrow + 16 * mi + c15) * LSTR + (ks << 5) + (q << 3);
                Ah[mi] = *(const s16x8*)(hb_hi + off);
                Al[mi] = *(const s16x8*)(hb_lo + off);
            }
            #pragma unroll
            for (int tn = 0; tn < 4; ++tn) {
                const u16* wp = wb + (wcol + (tn << 4) + c15) * 512 + (ks << 5) + (q << 3);
                s16x8 Bh = *(const s16x8*)wp;
                s16x8 Bl = *(const s16x8*)(wp + 256);
                #pragma unroll
                for (int mi = 0; mi < 2; ++mi) {
                    acc[mi][tn] = __builtin_amdgcn_mfma_f32_16x16x32_bf16(Ah[mi], Bh, acc[mi][tn], 0, 0, 0);
                    acc[mi][tn] = __builtin_amdgcn_mfma_f32_16x16x32_bf16(Al[mi], Bh, acc[mi][tn], 0, 0, 0);
                    acc[mi][tn] = __builtin_amdgcn_mfma_f32_16x16x32_bf16(Ah[mi], Bl, acc[mi][tn], 0, 0, 0);
                }
            }
        }
    };

    #pragma unroll 1
    for (int l = 0; l < NLAYER; ++l) {
        // ---- P1: GEMM1 (t = h@W1^T + b1) + fp32 anchor dots from h regs + tanh ----
        f32x4 acc[2][4];
        #pragma unroll
        for (int mi = 0; mi < 2; ++mi)
          #pragma unroll
          for (int tn = 0; tn < 4; ++tn)
            acc[mi][tn] = (f32x4){b1c[tn], b1c[tn], b1c[tn], b1c[tn]};
        gemm3(ws, acc);
        // dots: praw[row][a] = h_reg . a_n  (col-split: this wave covers its 64 cols)
        #pragma unroll
        for (int mi = 0; mi < 2; ++mi) {
            #pragma unroll
            for (int rg = 0; rg < 4; ++rg) {
                float p0 = 0.f, p1 = 0.f, p2 = 0.f;
                #pragma unroll
                for (int tn = 0; tn < 4; ++tn) {
                    float hv = h[mi][tn][rg];
                    p0 = fmaf(hv, an[0][tn], p0);
                    p1 = fmaf(hv, an[1][tn], p1);
                    p2 = fmaf(hv, an[2][tn], p2);
                }
                #pragma unroll
                for (int m = 1; m < 16; m <<= 1) {
                    p0 += __shfl_xor(p0, m);
                    p1 += __shfl_xor(p1, m);
                    p2 += __shfl_xor(p2, m);
                }
                if (c15 < 3) {
                    float pv = (c15 == 0) ? p0 : ((c15 == 1) ? p1 : p2);
                    dpart[(wc * 3 + c15) * MROWS + wrow + 16 * mi + (q << 2) + rg] = pv;
                }
            }
        }
        #pragma unroll
        for (int mi = 0; mi < 2; ++mi)
          #pragma unroll
          for (int tn = 0; tn < 4; ++tn)
            #pragma unroll
            for (int rg = 0; rg < 4; ++rg)
              acc[mi][tn][rg] = ftanh(acc[mi][tn][rg]);
        __syncthreads();                       // B1: hb reads done, dpart visible

        // ---- P2: write z hi/lo into planes; threads t<64 compute per-row scalars + traces ----
        #pragma unroll
        for (int mi = 0; mi < 2; ++mi)
          #pragma unroll
          for (int tn = 0; tn < 4; ++tn)
            #pragma unroll
            for (int rg = 0; rg < 4; ++rg) {
                int off = (wrow + 16 * mi + (q << 2) + rg) * LSTR + wcol + (tn << 4) + c15;
                float zv = acc[mi][tn][rg];
                u16 hi = f2bf(zv);
                hb_hi[off] = hi;
                hb_lo[off] = f2bf(zv - bf2f(hi));
            }
        if (t < MROWS) {
            int r = t;
            float s  = scal[(r << 3) + 4];               // clamp scale of current h
            float ss = scal[(r << 3) + 5];               // ||h||^2 (clamped)
            float rs = 1.f / fmaxf(sqrtf(ss), 1e-12f);
            float cs[3], alpha = 0.f;
            long tb = (long)l * BTOT * 3 + (row0 + r) * 3;
            #pragma unroll
            for (int a = 0; a < 3; ++a) {
                float praw = dpart[(0 * 3 + a) * MROWS + r] + dpart[(1 * 3 + a) * MROWS + r]
                           + dpart[(2 * 3 + a) * MROWS + r] + dpart[(3 * 3 + a) * MROWS + r];
                float d     = s * praw;                  // clamped-h dot
                float align = d * rs;
                float div   = 1.f - align;
                float dist  = sqrtf(fmaxf(ss - 2.f * d + 1.f, 0.f));   // ||h - a_n||
                float c     = -0.1f * div / fmaxf(dist, 1e-12f);
                cs[a] = c; alpha += c;
                out[A0 + tb + a]           = align;
                out[A0 + TRL + tb + a]     = div;
                out[A0 + 2 * TRL + tb + a] = fabsf(div);
            }
            f32x4 sv = {alpha, cs[0], cs[1], cs[2]};
            *(f32x4*)(scal + (r << 3)) = sv;             // leaves +4/+5 untouched
        }
        __syncthreads();                       // B2: z + scalars ready

        // ---- P3: GEMM2 (delta = z@W2^T + b2) + fused update into fp32 h regs ----
        #pragma unroll
        for (int mi = 0; mi < 2; ++mi)
          #pragma unroll
          for (int tn = 0; tn < 4; ++tn)
            acc[mi][tn] = (f32x4){b2c[tn], b2c[tn], b2c[tn], b2c[tn]};
        gemm3(ws + W2OFF, acc);
        // h_new = s*(1+alpha)*h + delta - sum_a c_a * a_n[a]   (s = deferred clamp)
        #pragma unroll
        for (int mi = 0; mi < 2; ++mi) {
            #pragma unroll
            for (int rg = 0; rg < 4; ++rg) {
                int r = wrow + 16 * mi + (q << 2) + rg;
                f32x4 sv = *(const f32x4*)(scal + (r << 3));     // alpha,c0,c1,c2
                float s  = scal[(r << 3) + 4];
                float sa = s * (1.f + sv[0]);
                #pragma unroll
                for (int tn = 0; tn < 4; ++tn) {
                    float comb = sv[1] * an[0][tn] + sv[2] * an[1][tn] + sv[3] * an[2][tn];
                    h[mi][tn][rg] = fmaf(sa, h[mi][tn][rg], acc[mi][tn][rg] - comb);
                }
            }
        }
        __syncthreads();                       // B3: all z reads done

        // ---- P4: write h_new (unclamped) hi/lo to planes ----
        #pragma unroll
        for (int mi = 0; mi < 2; ++mi)
          #pragma unroll
          for (int tn = 0; tn < 4; ++tn)
            #pragma unroll
            for (int rg = 0; rg < 4; ++rg) {
                int off = (wrow + 16 * mi + (q << 2) + rg) * LSTR + wcol + (tn << 4) + c15;
                float hv = h[mi][tn][rg];
                u16 hi = f2bf(hv);
                hb_hi[off] = hi;
                hb_lo[off] = f2bf(hv - bf2f(hi));
            }
        __syncthreads();                       // B4: h_new visible

        // ---- P5: row-norm clamp in-place; publish s, ss for next layer ----
        {
            u16* rh = hb_hi + rr * LSTR + (ch << 5);
            u16* rl = hb_lo + rr * LSTR + (ch << 5);
            float ss = 0.f;
            #pragma unroll
            for (int j = 0; j < 4; ++j) {
                s16x8 vh = *(const s16x8*)(rh + (j << 3));
                s16x8 vl = *(const s16x8*)(rl + (j << 3));
                #pragma unroll
                for (int e = 0; e < 8; ++e) {
                    float f = bf2f((u16)vh[e]) + bf2f((u16)vl[e]);
                    ss = fmaf(f, f, ss);
                }
            }
            ss += __shfl_xor(ss, 1);
            ss += __shfl_xor(ss, 2);
            ss += __shfl_xor(ss, 4);
            float nn = sqrtf(ss);
            float s  = (nn > 10.f) ? (10.f / (nn + 1e-8f)) : 1.f;
            if (ch == 0) { scal[(rr << 3) + 4] = s; scal[(rr << 3) + 5] = ss * s * s; }
            if (s != 1.f) {
                #pragma unroll
                for (int j = 0; j < 4; ++j) {
                    s16x8 vh = *(const s16x8*)(rh + (j << 3));
                    s16x8 vl = *(const s16x8*)(rl + (j << 3));
                    #pragma unroll
                    for (int e = 0; e < 8; ++e) {
                        float f = (bf2f((u16)vh[e]) + bf2f((u16)vl[e])) * s;
                        u16 hi = f2bf(f);
                        vh[e] = (short)hi;
                        vl[e] = (short)f2bf(f - bf2f(hi));
                    }
                    *(s16x8*)(rh + (j << 3)) = vh;
                    *(s16x8*)(rl + (j << 3)) = vl;
                }
            }
        }
        __syncthreads();                       // B5: clamped h ready for next layer
    }

    // ---- coalesced fp32 h_final output (planes hold clamped final h) ----
    {
        const u16* sh = hb_hi + rr * LSTR + (ch << 5);
        const u16* sl = hb_lo + rr * LSTR + (ch << 5);
        f32x4* dst = (f32x4*)(out + (row0 + rr) * DIM + (ch << 5));
        #pragma unroll
        for (int j = 0; j < 4; ++j) {
            s16x8 vh = *(const s16x8*)(sh + (j << 3));
            s16x8 vl = *(const s16x8*)(sl + (j << 3));
            f32x4 o0, o1;
            #pragma unroll
            for (int e = 0; e < 4; ++e) o0[e] = bf2f((u16)vh[e]) + bf2f((u16)vl[e]);
            #pragma unroll
            for (int e = 0; e < 4; ++e) o1[e] = bf2f((u16)vh[4 + e]) + bf2f((u16)vl[4 + e]);
            dst[2 * j]     = o0;
            dst[2 * j + 1] = o1;
        }
    }
}

extern "C" void kernel_launch(void* const* d_in, const int* in_sizes, int n_in,
                              void* d_out, int out_size, void* d_ws, size_t ws_size,
                              hipStream_t stream) {
    const float* h0 = (const float*)d_in[0];
    const float* W1 = (const float*)d_in[1];
    const float* b1 = (const float*)d_in[2];
    const float* W2 = (const float*)d_in[3];
    const float* b2 = (const float*)d_in[4];
    const float* an = (const float*)d_in[5];
    u16*   ws  = (u16*)d_ws;
    float* out = (float*)d_out;

    wsplit_kernel<<<dim3(DIM * DIM / 256), dim3(256), 0, stream>>>(W1, W2, ws);
    collapse_kernel<<<dim3(BTOT / MROWS), dim3(NTHR), 0, stream>>>(h0, b1, b2, an, ws, out);
}

// Round 3
// 1408.553 us; speedup vs baseline: 3.0425x; 3.0425x over previous
//
#include <hip/hip_runtime.h>

typedef unsigned short u16;
typedef float    f32x4 __attribute__((ext_vector_type(4)));
typedef short    s16x8 __attribute__((ext_vector_type(8)));
typedef _Float16 f16x8 __attribute__((ext_vector_type(8)));

#define BTOT    131072
#define DIM     256
#define NLAYER  6
#define MROWS   128           // rows per block (8 waves: 2 row-groups x 4 col-groups)
#define NTHR    512
#define LSTR    264           // padded fp16 row stride (16B-aligned rows; 2-way bank alias = free)
#define W2OFF   65536         // u16 elements: W2 block offset inside d_ws (single fp16 plane per matrix)

__device__ __forceinline__ float h2f(u16 u) {
    union { u16 u; _Float16 h; } v; v.u = u; return (float)v.h;
}
__device__ __forceinline__ u16 f2h(float f) {
    union { _Float16 h; u16 u; } v; v.h = (_Float16)f; return v.u;   // RNE
}
__device__ __forceinline__ float ftanh(float x) {
    float e = __expf(2.0f * x);          // inf-safe: e=inf -> 1, e=0 -> -1
    return 1.0f - 2.0f / (e + 1.0f);
}

// Pre-convert W1/W2 (fp32) into single fp16 planes, row-major per output row:
// ws[n*256 + k] = fp16(W[n][k]).  B error 2^-12 rel; A carries hi+lo fp16 (22 bits).
__global__ void wsplit_kernel(const float* __restrict__ W1, const float* __restrict__ W2,
                              u16* __restrict__ ws) {
    int i = blockIdx.x * 256 + threadIdx.x;      // 0..65535
    ws[i]         = f2h(W1[i]);
    ws[W2OFF + i] = f2h(W2[i]);
}

__global__ __launch_bounds__(NTHR) __attribute__((amdgpu_waves_per_eu(2, 2)))
void collapse_kernel(const float* __restrict__ h0,
                     const float* __restrict__ b1g,
                     const float* __restrict__ b2g,
                     const float* __restrict__ ancg,
                     const u16*  __restrict__ ws,
                     float* __restrict__ out)
{
    __shared__ u16   hb_hi[MROWS * LSTR];   // 67584 B: A-operand fp16 hi plane (h / z / h_new, time-shared)
    __shared__ u16   hb_lo[MROWS * LSTR];   // 67584 B: fp16 lo plane (residual)
    __shared__ float dpart[12 * MROWS];     //  6144 B: anchor-dot partials [wc*3+a][row]
    __shared__ float scal[MROWS * 8];       //  4096 B: per-row {alpha,c0,c1,c2, s, ss}
    __shared__ float anch_inv[3];

    const int t    = threadIdx.x;
    const int w    = t >> 6;                // wave 0..7
    const int ln   = t & 63;
    const int wr   = w >> 2;                // row-group 0..1 (64 rows each)
    const int wc   = w & 3;                 // col-group 0..3 (64 cols each)
    const int c15  = ln & 15;
    const int q    = ln >> 4;
    const int wcol = wc << 6;               // wave's 64-col slice
    const int wrow = wr << 6;               // wave's 64-row slice
    const int rr   = t >> 2;                // row-thread: row 0..127
    const int ch   = t & 3;                 // row-thread: 64-col chunk
    const long row0 = (long)blockIdx.x * MROWS;

    // ---------------- bootstrap ----------------
    {   // coalesced fp32 h0 -> split fp16 hi/lo planes; per-row ||h0||^2
        const f32x4* src = (const f32x4*)(h0 + (row0 + rr) * DIM + (ch << 6));
        u16* dh = hb_hi + rr * LSTR + (ch << 6);
        u16* dl = hb_lo + rr * LSTR + (ch << 6);
        float ss = 0.f;
        #pragma unroll
        for (int j = 0; j < 8; ++j) {
            f32x4 v0 = src[2 * j], v1 = src[2 * j + 1];
            s16x8 vh, vl;
            #pragma unroll
            for (int e = 0; e < 4; ++e) {
                float f = v0[e]; ss = fmaf(f, f, ss);
                u16 hi = f2h(f); vh[e] = (short)hi; vl[e] = (short)f2h(f - h2f(hi));
            }
            #pragma unroll
            for (int e = 0; e < 4; ++e) {
                float f = v1[e]; ss = fmaf(f, f, ss);
                u16 hi = f2h(f); vh[4 + e] = (short)hi; vl[4 + e] = (short)f2h(f - h2f(hi));
            }
            *(s16x8*)(dh + (j << 3)) = vh;
            *(s16x8*)(dl + (j << 3)) = vl;
        }
        ss += __shfl_xor(ss, 1);
        ss += __shfl_xor(ss, 2);
        if (ch == 0) { scal[(rr << 3) + 4] = 1.f; scal[(rr << 3) + 5] = ss; }
    }
    if (w < 3) {                            // waves 0..2: anchor inverse norms (fp32)
        float ssa = 0.f;
        #pragma unroll
        for (int j = 0; j < 4; ++j) {
            float v = ancg[w * DIM + (ln << 2) + j];
            ssa = fmaf(v, v, ssa);
        }
        #pragma unroll
        for (int m = 1; m < 64; m <<= 1) ssa += __shfl_xor(ssa, m);
        if (ln == 0) anch_inv[w] = 1.f / fmaxf(sqrtf(ssa), 1e-12f);
    }
    __syncthreads();

    // owners: fp32 h registers in MFMA C-layout (row=wrow+16mi+4q+rg, col=wcol+16tn+c15)
    f32x4 h[4][4];
    #pragma unroll
    for (int mi = 0; mi < 4; ++mi)
      #pragma unroll
      for (int tn = 0; tn < 4; ++tn)
        #pragma unroll
        for (int rg = 0; rg < 4; ++rg) {
            int off = (wrow + 16 * mi + (q << 2) + rg) * LSTR + wcol + (tn << 4) + c15;
            h[mi][tn][rg] = h2f(hb_hi[off]) + h2f(hb_lo[off]);
        }
    float an[3][4], b1c[4], b2c[4];
    #pragma unroll
    for (int tn = 0; tn < 4; ++tn) {
        int c = wcol + (tn << 4) + c15;
        an[0][tn] = ancg[0 * DIM + c] * anch_inv[0];
        an[1][tn] = ancg[1 * DIM + c] * anch_inv[1];
        an[2][tn] = ancg[2 * DIM + c] * anch_inv[2];
        b1c[tn]   = b1g[c];
        b2c[tn]   = b2g[c];
    }

    const long A0  = (long)BTOT * DIM;          // traces base
    const long TRL = (long)NLAYER * BTOT * 3;   // one trace array length

    // fp16x2 GEMM: acc += (Ahi+Alo)@B, B single fp16 plane. A from LDS planes, B from ws.
    auto gemm2 = [&](const u16* wb, f32x4 (&acc)[4][4]) {
        #pragma unroll
        for (int ks = 0; ks < 8; ++ks) {
            f16x8 Ah[4], Al[4];
            #pragma unroll
            for (int mi = 0; mi < 4; ++mi) {
                int off = (wrow + 16 * mi + c15) * LSTR + (ks << 5) + (q << 3);
                Ah[mi] = *(const f16x8*)(hb_hi + off);
                Al[mi] = *(const f16x8*)(hb_lo + off);
            }
            #pragma unroll
            for (int tn = 0; tn < 4; ++tn) {
                const u16* wp = wb + (wcol + (tn << 4) + c15) * 256 + (ks << 5) + (q << 3);
                f16x8 B = *(const f16x8*)wp;
                #pragma unroll
                for (int mi = 0; mi < 4; ++mi) {
                    acc[mi][tn] = __builtin_amdgcn_mfma_f32_16x16x32_f16(Ah[mi], B, acc[mi][tn], 0, 0, 0);
                    acc[mi][tn] = __builtin_amdgcn_mfma_f32_16x16x32_f16(Al[mi], B, acc[mi][tn], 0, 0, 0);
                }
            }
        }
    };

    #pragma unroll 1
    for (int l = 0; l < NLAYER; ++l) {
        // ---- P1: GEMM1 (t = h@W1^T + b1) + fp32 anchor dots from h regs + tanh ----
        f32x4 acc[4][4];
        #pragma unroll
        for (int mi = 0; mi < 4; ++mi)
          #pragma unroll
          for (int tn = 0; tn < 4; ++tn)
            acc[mi][tn] = (f32x4){b1c[tn], b1c[tn], b1c[tn], b1c[tn]};
        gemm2(ws, acc);
        // dots: praw[row][a] = h_reg . a_n  (col-split: this wave covers its 64 cols)
        #pragma unroll
        for (int mi = 0; mi < 4; ++mi) {
            #pragma unroll
            for (int rg = 0; rg < 4; ++rg) {
                float p0 = 0.f, p1 = 0.f, p2 = 0.f;
                #pragma unroll
                for (int tn = 0; tn < 4; ++tn) {
                    float hv = h[mi][tn][rg];
                    p0 = fmaf(hv, an[0][tn], p0);
                    p1 = fmaf(hv, an[1][tn], p1);
                    p2 = fmaf(hv, an[2][tn], p2);
                }
                #pragma unroll
                for (int m = 1; m < 16; m <<= 1) {
                    p0 += __shfl_xor(p0, m);
                    p1 += __shfl_xor(p1, m);
                    p2 += __shfl_xor(p2, m);
                }
                if (c15 < 3) {
                    float pv = (c15 == 0) ? p0 : ((c15 == 1) ? p1 : p2);
                    dpart[(wc * 3 + c15) * MROWS + wrow + 16 * mi + (q << 2) + rg] = pv;
                }
            }
        }
        #pragma unroll
        for (int mi = 0; mi < 4; ++mi)
          #pragma unroll
          for (int tn = 0; tn < 4; ++tn)
            #pragma unroll
            for (int rg = 0; rg < 4; ++rg)
              acc[mi][tn][rg] = ftanh(acc[mi][tn][rg]);
        __syncthreads();                       // B1: hb reads done, dpart visible

        // ---- P2: write z hi/lo into planes; threads t<128 compute per-row scalars + traces ----
        #pragma unroll
        for (int mi = 0; mi < 4; ++mi)
          #pragma unroll
          for (int tn = 0; tn < 4; ++tn)
            #pragma unroll
            for (int rg = 0; rg < 4; ++rg) {
                int off = (wrow + 16 * mi + (q << 2) + rg) * LSTR + wcol + (tn << 4) + c15;
                float zv = acc[mi][tn][rg];
                u16 hi = f2h(zv);
                hb_hi[off] = hi;
                hb_lo[off] = f2h(zv - h2f(hi));
            }
        if (t < MROWS) {
            int r = t;
            float s  = scal[(r << 3) + 4];               // clamp scale of current h
            float ss = scal[(r << 3) + 5];               // ||h||^2 (clamped)
            float rs = 1.f / fmaxf(sqrtf(ss), 1e-12f);
            float cs[3], alpha = 0.f;
            long tb = (long)l * BTOT * 3 + (row0 + r) * 3;
            #pragma unroll
            for (int a = 0; a < 3; ++a) {
                float praw = dpart[(0 * 3 + a) * MROWS + r] + dpart[(1 * 3 + a) * MROWS + r]
                           + dpart[(2 * 3 + a) * MROWS + r] + dpart[(3 * 3 + a) * MROWS + r];
                float d     = s * praw;                  // clamped-h dot
                float align = d * rs;
                float div   = 1.f - align;
                float dist  = sqrtf(fmaxf(ss - 2.f * d + 1.f, 0.f));   // ||h - a_n||
                float c     = -0.1f * div / fmaxf(dist, 1e-12f);
                cs[a] = c; alpha += c;
                out[A0 + tb + a]           = align;
                out[A0 + TRL + tb + a]     = div;
                out[A0 + 2 * TRL + tb + a] = fabsf(div);
            }
            f32x4 sv = {alpha, cs[0], cs[1], cs[2]};
            *(f32x4*)(scal + (r << 3)) = sv;             // leaves +4/+5 untouched
        }
        __syncthreads();                       // B2: z + scalars ready

        // ---- P3: GEMM2 (delta = z@W2^T + b2) + fused update into fp32 h regs ----
        #pragma unroll
        for (int mi = 0; mi < 4; ++mi)
          #pragma unroll
          for (int tn = 0; tn < 4; ++tn)
            acc[mi][tn] = (f32x4){b2c[tn], b2c[tn], b2c[tn], b2c[tn]};
        gemm2(ws + W2OFF, acc);
        // h_new = s*(1+alpha)*h + delta - sum_a c_a * a_n[a]   (s = deferred clamp)
        #pragma unroll
        for (int mi = 0; mi < 4; ++mi) {
            #pragma unroll
            for (int rg = 0; rg < 4; ++rg) {
                int r = wrow + 16 * mi + (q << 2) + rg;
                f32x4 sv = *(const f32x4*)(scal + (r << 3));     // alpha,c0,c1,c2
                float s  = scal[(r << 3) + 4];
                float sa = s * (1.f + sv[0]);
                #pragma unroll
                for (int tn = 0; tn < 4; ++tn) {
                    float comb = sv[1] * an[0][tn] + sv[2] * an[1][tn] + sv[3] * an[2][tn];
                    h[mi][tn][rg] = fmaf(sa, h[mi][tn][rg], acc[mi][tn][rg] - comb);
                }
            }
        }
        __syncthreads();                       // B3: all z reads done

        // ---- P4: write h_new (unclamped) hi/lo to planes ----
        #pragma unroll
        for (int mi = 0; mi < 4; ++mi)
          #pragma unroll
          for (int tn = 0; tn < 4; ++tn)
            #pragma unroll
            for (int rg = 0; rg < 4; ++rg) {
                int off = (wrow + 16 * mi + (q << 2) + rg) * LSTR + wcol + (tn << 4) + c15;
                float hv = h[mi][tn][rg];
                u16 hi = f2h(hv);
                hb_hi[off] = hi;
                hb_lo[off] = f2h(hv - h2f(hi));
            }
        __syncthreads();                       // B4: h_new visible

        // ---- P5: row-norm clamp in-place; publish s, ss for next layer ----
        {
            u16* rh = hb_hi + rr * LSTR + (ch << 6);
            u16* rl = hb_lo + rr * LSTR + (ch << 6);
            float ss = 0.f;
            #pragma unroll
            for (int j = 0; j < 8; ++j) {
                s16x8 vh = *(const s16x8*)(rh + (j << 3));
                s16x8 vl = *(const s16x8*)(rl + (j << 3));
                #pragma unroll
                for (int e = 0; e < 8; ++e) {
                    float f = h2f((u16)vh[e]) + h2f((u16)vl[e]);
                    ss = fmaf(f, f, ss);
                }
            }
            ss += __shfl_xor(ss, 1);
            ss += __shfl_xor(ss, 2);
            float nn = sqrtf(ss);
            float s  = (nn > 10.f) ? (10.f / (nn + 1e-8f)) : 1.f;
            if (ch == 0) { scal[(rr << 3) + 4] = s; scal[(rr << 3) + 5] = ss * s * s; }
            if (s != 1.f) {
                #pragma unroll
                for (int j = 0; j < 8; ++j) {
                    s16x8 vh = *(const s16x8*)(rh + (j << 3));
                    s16x8 vl = *(const s16x8*)(rl + (j << 3));
                    #pragma unroll
                    for (int e = 0; e < 8; ++e) {
                        float f = (h2f((u16)vh[e]) + h2f((u16)vl[e])) * s;
                        u16 hi = f2h(f);
                        vh[e] = (short)hi;
                        vl[e] = (short)f2h(f - h2f(hi));
                    }
                    *(s16x8*)(rh + (j << 3)) = vh;
                    *(s16x8*)(rl + (j << 3)) = vl;
                }
            }
        }
        __syncthreads();                       // B5: clamped h ready for next layer
    }

    // ---- coalesced fp32 h_final output (planes hold clamped final h) ----
    {
        const u16* sh = hb_hi + rr * LSTR + (ch << 6);
        const u16* sl = hb_lo + rr * LSTR + (ch << 6);
        f32x4* dst = (f32x4*)(out + (row0 + rr) * DIM + (ch << 6));
        #pragma unroll
        for (int j = 0; j < 8; ++j) {
            s16x8 vh = *(const s16x8*)(sh + (j << 3));
            s16x8 vl = *(const s16x8*)(sl + (j << 3));
            f32x4 o0, o1;
            #pragma unroll
            for (int e = 0; e < 4; ++e) o0[e] = h2f((u16)vh[e]) + h2f((u16)vl[e]);
            #pragma unroll
            for (int e = 0; e < 4; ++e) o1[e] = h2f((u16)vh[4 + e]) + h2f((u16)vl[4 + e]);
            dst[2 * j]     = o0;
            dst[2 * j + 1] = o1;
        }
    }
}

extern "C" void kernel_launch(void* const* d_in, const int* in_sizes, int n_in,
                              void* d_out, int out_size, void* d_ws, size_t ws_size,
                              hipStream_t stream) {
    const float* h0 = (const float*)d_in[0];
    const float* W1 = (const float*)d_in[1];
    const float* b1 = (const float*)d_in[2];
    const float* W2 = (const float*)d_in[3];
    const float* b2 = (const float*)d_in[4];
    const float* an = (const float*)d_in[5];
    u16*   ws  = (u16*)d_ws;
    float* out = (float*)d_out;

    wsplit_kernel<<<dim3(DIM * DIM / 256), dim3(256), 0, stream>>>(W1, W2, ws);
    collapse_kernel<<<dim3(BTOT / MROWS), dim3(NTHR), 0, stream>>>(h0, b1, b2, an, ws, out);
}